// Round 2
// baseline (340.884 us; speedup 1.0000x reference)
//
#include <hip/hip_runtime.h>

#define WS 7
#define BB 8
#define HH 384
#define WW 384
#define PP 377           // HH - WS
#define NC 48            // WS*WS - 1
#define STRIDE 49        // floats per site in LDS (odd -> conflict-free reads)
#define NSITE PP         // 377 sites per row
#define NX4 (PP * 12)    // 4524 float4 of X per row

// M[n][k] = (k==0) ? 1 : 2*cos(pi*(2n+1)*k/14), flattened row-major
__constant__ float d_M[49] = {
    1.0f,  1.9498558244f,  1.8019377358f,  1.5636629649f,  1.2469796037f,  0.8677674782f,  0.4450418679f,
    1.0f,  1.5636629649f,  0.4450418679f, -0.8677674782f, -1.8019377358f, -1.9498558244f, -1.2469796037f,
    1.0f,  0.8677674782f, -1.2469796037f, -1.9498558244f, -0.4450418679f,  1.5636629649f,  1.8019377358f,
    1.0f,  0.0f,          -2.0f,           0.0f,           2.0f,           0.0f,          -2.0f,
    1.0f, -0.8677674782f, -1.2469796037f,  1.9498558244f, -0.4450418679f, -1.5636629649f,  1.8019377358f,
    1.0f, -1.5636629649f,  0.4450418679f,  0.8677674782f, -1.8019377358f,  1.9498558244f, -1.2469796037f,
    1.0f, -1.9498558244f,  1.8019377358f, -1.5636629649f,  1.2469796037f, -0.8677674782f,  0.4450418679f,
};

__global__ __launch_bounds__(384) void idct_row_kernel(
    const float* __restrict__ X,
    const float* __restrict__ zf,
    float* __restrict__ out)
{
    __shared__ float lds[NSITE * STRIDE];   // 73,892 B
    __shared__ float ldsM[49];

    const int t   = threadIdx.x;            // 0..383
    const int row = blockIdx.x;             // 0..3071
    const int y   = row % HH;
    const int b   = row / HH;

    const size_t obase = (size_t)row * WW;

    // Last image row is all zeros; skip staging entirely (uniform branch).
    if (y == HH - 1) { out[obase + t] = 0.0f; return; }

    const int i = min(y, PP - 1);
    const size_t rbase = ((size_t)b * HH + i) * WW;       // site base in elements
    const float4* __restrict__ xrow = (const float4*)(X + rbase * NC);

    if (t < 49) ldsM[t] = d_M[t];

    // Stage the contiguous X row span: 4524 float4, fully coalesced.
    for (int q = t; q < NX4; q += 384) {
        float4 v = xrow[q];
        int j = q / 12;                 // site within row
        int m = q - j * 12;             // float4 index within site
        float* dst = &lds[j * STRIDE + 1 + 4 * m];
        dst[0] = v.x; dst[1] = v.y; dst[2] = v.z; dst[3] = v.w;
    }
    // Zero-frequency coefficient at site offset 0.
    if (t < NSITE) lds[t * STRIDE] = zf[rbase + t];

    __syncthreads();

    const int x  = t;
    const int j  = min(x, PP - 1);
    const int dx = x - j;               // 0..6 (nonzero only in last 7 cols)
    const int dy = y - i;               // 0..6 (uniform per block)

    const float* c  = &lds[j * STRIDE]; // c[t]: t=0 -> zf, t>=1 -> X[t-1]
    const float* wu = &ldsM[dy * 7];
    const float* wv = &ldsM[dx * 7];

    float acc = 0.0f;
#pragma unroll
    for (int u = 0; u < 7; ++u) {
        float s = 0.0f;
#pragma unroll
        for (int v = 0; v < 7; ++v)
            s = fmaf(wv[v], c[u * 7 + v], s);
        acc = fmaf(wu[u], s, acc);
    }

    if (x == WW - 1) acc = 0.0f;        // last column masked
    out[obase + x] = acc;
}

extern "C" void kernel_launch(void* const* d_in, const int* in_sizes, int n_in,
                              void* d_out, int out_size, void* d_ws, size_t ws_size,
                              hipStream_t stream) {
    const float* X  = (const float*)d_in[0];   // (8,384,384,48) fp32
    const float* zf = (const float*)d_in[1];   // (8,384,384,1)  fp32
    float* out = (float*)d_out;                // (8,384,384,1)  fp32

    idct_row_kernel<<<BB * HH, 384, 0, stream>>>(X, zf, out);
}

// Round 3
// 305.934 us; speedup vs baseline: 1.1142x; 1.1142x over previous
//
#include <hip/hip_runtime.h>

#define HH 384
#define WW 384
#define PP 377            // HH - 7
#define NC 48             // coeffs in X per site
#define NX4R (PP * 12)    // 4524 float4 of X per row

// M[n][k] = (k==0) ? 1 : 2*cos(pi*(2n+1)*k/14), flattened row-major (7x7)
__constant__ float d_M[49] = {
    1.0f,  1.9498558244f,  1.8019377358f,  1.5636629649f,  1.2469796037f,  0.8677674782f,  0.4450418679f,
    1.0f,  1.5636629649f,  0.4450418679f, -0.8677674782f, -1.8019377358f, -1.9498558244f, -1.2469796037f,
    1.0f,  0.8677674782f, -1.2469796037f, -1.9498558244f, -0.4450418679f,  1.5636629649f,  1.8019377358f,
    1.0f,  0.0f,          -2.0f,           0.0f,           2.0f,           0.0f,          -2.0f,
    1.0f, -0.8677674782f, -1.2469796037f,  1.9498558244f, -0.4450418679f, -1.5636629649f,  1.8019377358f,
    1.0f, -1.5636629649f,  0.4450418679f,  0.8677674782f, -1.8019377358f,  1.9498558244f, -1.2469796037f,
    1.0f, -1.9498558244f,  1.8019377358f, -1.5636629649f,  1.2469796037f, -0.8677674782f,  0.4450418679f,
};

__global__ __launch_bounds__(384) void idct_partial_kernel(
    const float* __restrict__ X,
    const float* __restrict__ zf,
    float* __restrict__ out)
{
    __shared__ float w49[49];
    __shared__ float part[PP * 13];   // 12 partials/site, stride 13 -> conflict-free

    const int t   = threadIdx.x;      // 0..383
    const int row = blockIdx.x;       // 0..3071
    const int y   = row % HH;
    const int b   = row / HH;
    const size_t obase = (size_t)row * WW;

    // Entire last image row is zero (uniform early-out, no sync needed).
    if (y == HH - 1) { out[obase + t] = 0.0f; return; }

    const int i  = min(y, PP - 1);
    const int dy = y - i;                             // block-uniform 0..6
    const size_t rbase = ((size_t)b * HH + i) * WW;   // site base (elements)

    // Block-uniform weight vector w[t] = M[dy][t/7] * M[0][t%7]
    if (t < 49) w49[t] = d_M[dy * 7 + t / 7] * d_M[t % 7];
    __syncthreads();

    // Each thread owns a fixed float4 phase m = t%12 (384 = 32*12).
    const int m  = t % 12;
    const int s0 = t / 12;
    const float wa = w49[1 + 4 * m];
    const float wb = w49[2 + 4 * m];
    const float wc = w49[3 + 4 * m];
    const float wd = w49[4 + 4 * m];

    const float4* __restrict__ xrow = (const float4*)(X + rbase * NC);

    // Pass 1a: issue all 12 coalesced loads (clamped index: no divergence).
    float4 v[12];
#pragma unroll
    for (int k = 0; k < 12; ++k) {
        int q = t + 384 * k;
        v[k] = xrow[q < NX4R ? q : (NX4R - 1)];
    }
    // Pass 1b: fold each float4 to one partial, scatter to LDS.
#pragma unroll
    for (int k = 0; k < 12; ++k) {
        int q = t + 384 * k;
        if (q < NX4R) {
            float p = fmaf(v[k].x, wa, fmaf(v[k].y, wb, fmaf(v[k].z, wc, v[k].w * wd)));
            part[(s0 + 32 * k) * 13 + m] = p;
        }
    }
    __syncthreads();

    // Pass 2: one output per thread.
    const int x = t;
    const int j = min(x, PP - 1);
    const float zv = zf[rbase + j];   // coalesced; zf weight is M[dy][0]*M[dx][0] = 1
    float acc;

    if (x < PP) {
        const float* p = &part[j * 13];   // lane stride 13 -> conflict-free
        float a0 = (p[0] + p[1]) + (p[2] + p[3]);
        float a1 = (p[4] + p[5]) + (p[6] + p[7]);
        float a2 = (p[8] + p[9]) + (p[10] + p[11]);
        acc = zv + (a0 + a1) + a2;
    } else if (x == WW - 1) {
        acc = 0.0f;                        // masked last column
    } else {
        // Tail columns x=377..382: dx != 0, full 49-tap recompute (6 lanes only).
        const int dx = x - (PP - 1);
        const float* __restrict__ c = X + (rbase + (PP - 1)) * NC;
        acc = 0.0f;
#pragma unroll
        for (int u = 0; u < 7; ++u) {
            float s = 0.0f;
#pragma unroll
            for (int vv = 0; vv < 7; ++vv) {
                int n = u * 7 + vv;
                float cv = (n == 0) ? zv : c[n - 1];
                s = fmaf(d_M[dx * 7 + vv], cv, s);
            }
            acc = fmaf(d_M[dy * 7 + u], s, acc);
        }
    }

    out[obase + x] = acc;
}

extern "C" void kernel_launch(void* const* d_in, const int* in_sizes, int n_in,
                              void* d_out, int out_size, void* d_ws, size_t ws_size,
                              hipStream_t stream) {
    const float* X  = (const float*)d_in[0];   // (8,384,384,48) fp32
    const float* zf = (const float*)d_in[1];   // (8,384,384,1)  fp32
    float* out = (float*)d_out;                // (8,384,384,1)  fp32

    idct_partial_kernel<<<8 * HH, 384, 0, stream>>>(X, zf, out);
}

// Round 4
// 305.679 us; speedup vs baseline: 1.1152x; 1.0008x over previous
//
#include <hip/hip_runtime.h>

#define HH 384
#define WW 384
#define PP 377            // HH - 7
#define NC 48             // coeffs in X per site
#define NX4R (PP * 12)    // 4524 float4 of X per row

// M[n][k] = (k==0) ? 1 : 2*cos(pi*(2n+1)*k/14), flattened row-major (7x7)
__constant__ float d_M[49] = {
    1.0f,  1.9498558244f,  1.8019377358f,  1.5636629649f,  1.2469796037f,  0.8677674782f,  0.4450418679f,
    1.0f,  1.5636629649f,  0.4450418679f, -0.8677674782f, -1.8019377358f, -1.9498558244f, -1.2469796037f,
    1.0f,  0.8677674782f, -1.2469796037f, -1.9498558244f, -0.4450418679f,  1.5636629649f,  1.8019377358f,
    1.0f,  0.0f,          -2.0f,           0.0f,           2.0f,           0.0f,          -2.0f,
    1.0f, -0.8677674782f, -1.2469796037f,  1.9498558244f, -0.4450418679f, -1.5636629649f,  1.8019377358f,
    1.0f, -1.5636629649f,  0.4450418679f,  0.8677674782f, -1.8019377358f,  1.9498558244f, -1.2469796037f,
    1.0f, -1.9498558244f,  1.8019377358f, -1.5636629649f,  1.2469796037f, -0.8677674782f,  0.4450418679f,
};

__global__ __launch_bounds__(384) void idct_partial_kernel(
    const float* __restrict__ X,
    const float* __restrict__ zf,
    float* __restrict__ out)
{
    __shared__ float w49[49];
    __shared__ float part[PP * 13];   // 12 partials/site, stride 13 -> conflict-free

    const int t   = threadIdx.x;      // 0..383
    const int row = blockIdx.x;       // 0..3071
    const int y   = row % HH;
    const int b   = row / HH;
    const size_t obase = (size_t)row * WW;

    // Entire last image row is zero (uniform early-out, no sync reached by any wave).
    if (y == HH - 1) { out[obase + t] = 0.0f; return; }

    const int i  = min(y, PP - 1);
    const int dy = y - i;                             // block-uniform 0..6
    const size_t rbase = ((size_t)b * HH + i) * WW;   // site base (elements)

    const float4* __restrict__ xrow = (const float4*)(X + rbase * NC);

    // ---- Issue ALL global loads first (12 X float4 + zf), fully coalesced ----
    float4 v[12];
#pragma unroll
    for (int k = 0; k < 12; ++k) {
        int q = t + 384 * k;
        v[k] = xrow[q < NX4R ? q : (NX4R - 1)];
    }
    const float zv = zf[rbase + min(t, PP - 1)];      // zf weight = M[dy][0]*M[dx][0] = 1

    // ---- Build block-uniform weights + barrier: hidden under vmcnt latency ----
    if (t < 49) w49[t] = d_M[dy * 7 + t / 7] * d_M[t % 7];
    __syncthreads();

    // Each thread owns a fixed float4 phase m = t%12 (384 = 32*12).
    const int m  = t % 12;
    const int s0 = t / 12;
    const float wa = w49[1 + 4 * m];
    const float wb = w49[2 + 4 * m];
    const float wc = w49[3 + 4 * m];
    const float wd = w49[4 + 4 * m];

    // Fold each float4 to one partial, scatter to LDS (near-consecutive -> ~free).
#pragma unroll
    for (int k = 0; k < 12; ++k) {
        int q = t + 384 * k;
        if (q < NX4R) {
            float p = fmaf(v[k].x, wa, fmaf(v[k].y, wb, fmaf(v[k].z, wc, v[k].w * wd)));
            part[(s0 + 32 * k) * 13 + m] = p;
        }
    }
    __syncthreads();

    // ---- Pass 2: one output per thread ----
    const int x = t;
    const int j = min(x, PP - 1);
    float acc;

    if (x < PP) {
        const float* p = &part[j * 13];   // lane stride 13 -> conflict-free
        float a0 = (p[0] + p[1]) + (p[2] + p[3]);
        float a1 = (p[4] + p[5]) + (p[6] + p[7]);
        float a2 = (p[8] + p[9]) + (p[10] + p[11]);
        acc = zv + (a0 + a1) + a2;
    } else if (x == WW - 1) {
        acc = 0.0f;                        // masked last column
    } else {
        // Tail columns x=377..382: dx != 0, full 49-tap recompute (6 lanes only, L1-hot).
        const int dx = x - (PP - 1);
        const float* __restrict__ c = X + (rbase + (PP - 1)) * NC;
        acc = 0.0f;
#pragma unroll
        for (int u = 0; u < 7; ++u) {
            float s = 0.0f;
#pragma unroll
            for (int vv = 0; vv < 7; ++vv) {
                int n = u * 7 + vv;
                float cv = (n == 0) ? zv : c[n - 1];
                s = fmaf(d_M[dx * 7 + vv], cv, s);
            }
            acc = fmaf(d_M[dy * 7 + u], s, acc);
        }
    }

    out[obase + x] = acc;
}

extern "C" void kernel_launch(void* const* d_in, const int* in_sizes, int n_in,
                              void* d_out, int out_size, void* d_ws, size_t ws_size,
                              hipStream_t stream) {
    const float* X  = (const float*)d_in[0];   // (8,384,384,48) fp32
    const float* zf = (const float*)d_in[1];   // (8,384,384,1)  fp32
    float* out = (float*)d_out;                // (8,384,384,1)  fp32

    idct_partial_kernel<<<8 * HH, 384, 0, stream>>>(X, zf, out);
}